// Round 3
// 862.941 us; speedup vs baseline: 1.1138x; 1.1138x over previous
//
#include <hip/hip_runtime.h>

// RWKV block on MI355X (gfx950).  B=8, T=2048, C=1024, M=16384.
// R6: fixed the R5 stage-schedule race.  R5 staged half (7+p) at phase p,
//     which overwrote the very half phase p was reading (DMA can land from
//     L2 in ~200cy while the phase's 96 queued ds_read_b128 take ~1100cy).
//     New stagger stages each half at the earliest phase strictly AFTER its
//     last read: p0:buf1.A1(t+1) p1:buf1.B1(t+1) p2:buf0.A0(t+2)
//     p3:buf0.B0(t+2) p4:buf0.A1(t+2) p5:buf0.B1(t+2) p6:buf1.A0(t+3)
//     p7:buf1.B0(t+3).  vmcnt(4) before barrier#2 of p=3/p=7 only
//     (reads at p4-7 need stages <=p1; reads at p0-3 next iter need <=p5).
//     Prologue: 6 stages (buf0 tile0 + buf1.A0/B0 tile1), vmcnt(4).
// R5: 256^2 8-phase counted-vmcnt schedule (m201 template), BK=64, 8 waves
//     (2Mx4N), 128 KiB LDS double-buffer, raw s_barrier, setprio around MFMA,
//     XOR-chunk LDS swizzle (bank-conflict-free, carried from R4).
// WKV: chunked parallel scan (R3).  LN/transpose kernels unchanged.

#define Bb 8
#define T 2048
#define C 1024
#define M (Bb*T)
#define LCH 32            // chunk length
#define NCH 64            // chunks per sequence (T/LCH)
#define NCI (Bb*NCH)      // 512 chunk instances
#define WKV_THREADS (NCI*C)   // 524288

typedef unsigned short u16;
typedef unsigned int u32;
typedef __bf16 bf16x8 __attribute__((ext_vector_type(8)));
typedef float f32x4 __attribute__((ext_vector_type(4)));
typedef u16 u16x4 __attribute__((ext_vector_type(4)));

__device__ __forceinline__ u16 f2bf(float f) {
    u32 u = __float_as_uint(f);
    u32 r = u + 0x7FFFu + ((u >> 16) & 1u);   // round-to-nearest-even
    return (u16)(r >> 16);
}
__device__ __forceinline__ float bf2f(u16 s) {
    return __uint_as_float(((u32)s) << 16);
}
__device__ __forceinline__ float sigmoidf_(float z) {
    return 1.0f / (1.0f + __expf(-z));
}
__device__ __forceinline__ void load_lds16(const void* g, void* l) {
    __builtin_amdgcn_global_load_lds(
        (const __attribute__((address_space(1))) void*)g,
        (__attribute__((address_space(3))) void*)l, 16, 0, 0);
}

// ---------------- weight transpose + cast: Wt[n][k] = bf16(W[k][n]) ----------------
__global__ __launch_bounds__(256) void transpose_cast_kernel(
    const float* __restrict__ W, u16* __restrict__ Wt, int K, int N)
{
    __shared__ float tile[32][33];
    const int bk = blockIdx.x * 32, bn = blockIdx.y * 32;
    const int tx = threadIdx.x, ty = threadIdx.y;   // (32,8)
    #pragma unroll
    for (int i = 0; i < 32; i += 8)
        tile[ty + i][tx] = W[(size_t)(bk + ty + i) * N + bn + tx];
    __syncthreads();
    #pragma unroll
    for (int i = 0; i < 32; i += 8)
        Wt[(size_t)(bn + ty + i) * K + bk + tx] = f2bf(tile[tx][ty + i]);
}

// ============ 256^2 8-phase GEMM mainloop (T2+T3+T4+T5) ============
// A (lda-major), Bt (ldb-major), bf16 row-major.  nkt = K/64 (even, pow2).
// LDS: 8 slots of 16 KiB: slot = buf*4 + mat*2 + half (A: slots 0,1; B: 2,3).
// Half-tile = 128 rows x 64 k, rows swizzled: row r chunk c holds global
// chunk c^(r&7) (chunk = 16B).  Staged linearly (dst = tid*16 / +8192).
// Per wave (wm=wave>>2, wn=wave&3): quadrant (a,b) covers
// rows a*128 + wm*64 + [0,64), cols b*128 + wn*32 + [0,32).
// Phase pp in 0..3 computes quadrant (pp>>1, pp&1) of K-tile buf=p>>2.
__device__ __forceinline__ void gemm256_mainloop(
    const u16* __restrict__ A, const int lda,
    const u16* __restrict__ Bt, const int ldb, const int nkt,
    const int m0, const int n0, u16* lds, f32x4 acc[2][2][4][2])
{
    const int tid  = threadIdx.x;
    const int wave = tid >> 6, lane = tid & 63;
    const int q = lane >> 4, m16 = lane & 15;
    const int wm = wave >> 2, wn = wave & 3;

    const f32x4 zero4 = {0.f, 0.f, 0.f, 0.f};
    #pragma unroll
    for (int i = 0; i < 2; ++i)
        #pragma unroll
        for (int j = 0; j < 2; ++j)
            #pragma unroll
            for (int k = 0; k < 4; ++k)
                #pragma unroll
                for (int l = 0; l < 2; ++l) acc[i][j][k][l] = zero4;

    // staging geometry: thread covers (row sr, chunk tid&7) and (+64 rows)
    const int sr = tid >> 3;                              // 0..63
    const int kc = ((tid & 7) ^ (sr & 7)) << 3;           // swizzled src chunk (shorts)
    const size_t abase = (size_t)(m0 + sr) * lda + kc;
    const size_t bbase = (size_t)(n0 + sr) * ldb + kc;
    const size_t lda64 = (size_t)lda << 6, ldb64 = (size_t)ldb << 6;
    char* ldsb = (char*)lds;
    const int dst0 = tid << 4;

#define STG_A(bufs, hf, k0) do { \
    char* d_ = ldsb + (((bufs) * 4 + (hf)) << 14) + dst0; \
    const u16* g_ = A + abase + (size_t)(hf) * 2 * lda64 + (k0); \
    load_lds16(g_, d_); load_lds16(g_ + lda64, d_ + 8192); } while (0)
#define STG_B(bufs, hf, k0) do { \
    char* d_ = ldsb + (((bufs) * 4 + 2 + (hf)) << 14) + dst0; \
    const u16* g_ = Bt + bbase + (size_t)(hf) * 2 * ldb64 + (k0); \
    load_lds16(g_, d_); load_lds16(g_ + ldb64, d_ + 8192); } while (0)

    // prologue: buf0 <- tile0 complete, buf1 <- tile1 A0,B0 (12 loads)
    STG_A(0, 0, 0);  STG_B(0, 0, 0);  STG_A(0, 1, 0);  STG_B(0, 1, 0);
    STG_A(1, 0, 64); STG_B(1, 0, 64);
    asm volatile("s_waitcnt vmcnt(4)" ::: "memory");   // buf0 tile0 landed
    __builtin_amdgcn_s_barrier();

    const int arow = ((wm << 6) + m16) << 6;   // shorts within half-tile
    const int brow = ((wn << 5) + m16) << 6;
    const int xh = m16 & 7;
    const int ch0 = (q ^ xh) << 3, ch1 = ((4 + q) ^ xh) << 3;

    #pragma unroll 1
    for (int kt2 = 0; kt2 < nkt; kt2 += 2) {
        #pragma unroll
        for (int p = 0; p < 8; ++p) {
            const int pp = p & 3, aa = pp >> 1, bbq = pp & 1, buf = p >> 2;
            const u16* Ap = lds + ((buf * 4 + aa) << 13) + arow;
            const u16* Bq = lds + ((buf * 4 + 2 + bbq) << 13) + brow;
            bf16x8 av[4][2], bv[2][2];
            #pragma unroll
            for (int mf = 0; mf < 4; ++mf) {
                av[mf][0] = *(const bf16x8*)&Ap[mf * 1024 + ch0];
                av[mf][1] = *(const bf16x8*)&Ap[mf * 1024 + ch1];
            }
            #pragma unroll
            for (int nf = 0; nf < 2; ++nf) {
                bv[nf][0] = *(const bf16x8*)&Bq[nf * 1024 + ch0];
                bv[nf][1] = *(const bf16x8*)&Bq[nf * 1024 + ch1];
            }
            // race-free stage stagger (each half staged strictly after the
            // last read of the contents it overwrites; k wraps in tail)
            {
                const int k1 = ((kt2 + 1) & (nkt - 1)) << 6;
                const int k2 = ((kt2 + 2) & (nkt - 1)) << 6;
                const int k3 = ((kt2 + 3) & (nkt - 1)) << 6;
                if (p == 0)      STG_A(1, 1, k1);   // buf1.A1 <- t+1
                else if (p == 1) STG_B(1, 1, k1);   // buf1.B1 <- t+1
                else if (p == 2) STG_A(0, 0, k2);   // buf0.A0 <- t+2
                else if (p == 3) STG_B(0, 0, k2);   // buf0.B0 <- t+2
                else if (p == 4) STG_A(0, 1, k2);   // buf0.A1 <- t+2
                else if (p == 5) STG_B(0, 1, k2);   // buf0.B1 <- t+2
                else if (p == 6) STG_A(1, 0, k3);   // buf1.A0 <- t+3
                else             STG_B(1, 0, k3);   // buf1.B0 <- t+3
            }
            __builtin_amdgcn_s_barrier();
            asm volatile("s_waitcnt lgkmcnt(0)" ::: "memory");
            __builtin_amdgcn_s_setprio(1);
            #pragma unroll
            for (int mf = 0; mf < 4; ++mf)
                #pragma unroll
                for (int nf = 0; nf < 2; ++nf) {
                    acc[aa][bbq][mf][nf] = __builtin_amdgcn_mfma_f32_16x16x32_bf16(
                        av[mf][0], bv[nf][0], acc[aa][bbq][mf][nf], 0, 0, 0);
                    acc[aa][bbq][mf][nf] = __builtin_amdgcn_mfma_f32_16x16x32_bf16(
                        av[mf][1], bv[nf][1], acc[aa][bbq][mf][nf], 0, 0, 0);
                }
            __builtin_amdgcn_s_setprio(0);
            // counted wait once per K-tile: reads of the next 4 phases only
            // need stages issued >=2 stages back (see stagger table)
            if (pp == 3) asm volatile("s_waitcnt vmcnt(4)" ::: "memory");
            __builtin_amdgcn_s_barrier();
        }
    }
    // drain DMA before LDS dealloc / epilogue
    asm volatile("s_waitcnt vmcnt(0)" ::: "memory");
#undef STG_A
#undef STG_B
}

// ---------------- LN1: xn = LN(x,g1,b1) as bf16 ----------------
__global__ __launch_bounds__(256) void ln1_kernel(
    const float* __restrict__ x, const float* __restrict__ g, const float* __restrict__ b,
    u16* __restrict__ xn)
{
    const int row = blockIdx.x, tid = threadIdx.x;
    const size_t base = (size_t)row * C;
    const int c = tid * 4;
    float4 v = *(const float4*)&x[base + c];
    float s  = v.x + v.y + v.z + v.w;
    float s2 = v.x*v.x + v.y*v.y + v.z*v.z + v.w*v.w;
    #pragma unroll
    for (int off = 32; off >= 1; off >>= 1) { s += __shfl_xor(s, off); s2 += __shfl_xor(s2, off); }
    __shared__ float red[8];
    const int wave = tid >> 6, lane = tid & 63;
    if (lane == 0) { red[wave] = s; red[4 + wave] = s2; }
    __syncthreads();
    const float sum  = red[0] + red[1] + red[2] + red[3];
    const float sums = red[4] + red[5] + red[6] + red[7];
    const float mean = sum * (1.0f / C);
    const float var  = sums * (1.0f / C) - mean * mean;
    const float rstd = rsqrtf(var + 1e-5f);
    float4 gv = *(const float4*)&g[c];
    float4 bv = *(const float4*)&b[c];
    u16x4 o;
    o.x = f2bf((v.x - mean) * rstd * gv.x + bv.x);
    o.y = f2bf((v.y - mean) * rstd * gv.y + bv.y);
    o.z = f2bf((v.z - mean) * rstd * gv.z + bv.z);
    o.w = f2bf((v.w - mean) * rstd * gv.w + bv.w);
    *(u16x4*)&xn[base + c] = o;
}

// ---------------- GEMM1 + time-mix epilogue -> packed kv (dword) + r (bf16) ----------------
__global__ __launch_bounds__(512, 2) void gemm1_kernel(
    const u16* __restrict__ xn, const u16* __restrict__ wt,
    const float* __restrict__ x,
    const float* __restrict__ tmk, const float* __restrict__ tmv, const float* __restrict__ tmr,
    u16* __restrict__ kvbuf, u16* __restrict__ rbuf)
{
    __shared__ __align__(16) u16 lds[8 * 8192];   // 128 KiB
    f32x4 acc[2][2][4][2];
    const int nbn = 12;
    int id = blockIdx.x;
    id = (id & 7) * (768 >> 3) + (id >> 3);       // XCD-aware swizzle (768 % 8 == 0)
    const int m0 = (id / nbn) << 8, n0 = (id % nbn) << 8;
    gemm256_mainloop(xn, C, wt, C, 16, m0, n0, lds, acc);

    const int tid = threadIdx.x, wave = tid >> 6, lane = tid & 63;
    const int q = lane >> 4, m16 = lane & 15;
    const int wm = wave >> 2, wn = wave & 3;
    const int grp = n0 >> 10;                     // 0=k, 1=v, 2=r (uniform per block)
    #pragma unroll
    for (int a2 = 0; a2 < 2; ++a2)
    #pragma unroll
    for (int mf = 0; mf < 4; ++mf)
    #pragma unroll
    for (int rg = 0; rg < 4; ++rg) {
        const int row = m0 + a2 * 128 + wm * 64 + mf * 16 + q * 4 + rg;
        const int t = row & (T - 1);
        const size_t rowp = (size_t)(t ? row - 1 : row) * C;   // time-mix x_prev row
        #pragma unroll
        for (int b2 = 0; b2 < 2; ++b2)
        #pragma unroll
        for (int nf = 0; nf < 2; ++nf) {
            const int cc = (n0 + b2 * 128 + wn * 32 + nf * 16 + m16) & (C - 1);
            const float val = acc[a2][b2][mf][nf][rg];
            const float xp = x[rowp + cc];
            if (grp == 0) {
                const float f = tmk[cc];
                kvbuf[(size_t)row * 2048 + 2 * cc] = f2bf(val * f + xp * (1.0f - f));
            } else if (grp == 1) {
                const float f = tmv[cc];
                kvbuf[(size_t)row * 2048 + 2 * cc + 1] = f2bf(val * f + xp * (1.0f - f));
            } else {
                const float f = tmr[cc];
                rbuf[(size_t)row * C + cc] = f2bf(sigmoidf_(val * f + xp * (1.0f - f)));
            }
        }
    }
}

// ================= WKV chunked parallel scan =================
__global__ __launch_bounds__(256) void wkv_k1(
    const u32* __restrict__ kvp, const float* __restrict__ wdec, float* __restrict__ bc)
{
    const int tid = blockIdx.x * 256 + threadIdx.x;
    const int c = tid & (C - 1), ci = tid >> 10;
    const float w = wdec[c];
    const size_t L = ((size_t)(ci >> 6) * T + (size_t)(ci & (NCH - 1)) * LCH) * C + c;
    float bb = -1e38f;
    #pragma unroll 4
    for (int t = 0; t < LCH; ++t) {
        const float k = bf2f((u16)(kvp[L + (size_t)t * C] & 0xffffu));
        const float ww = w + bb;
        const float p = fmaxf(ww, k);
        const float e1 = __expf(ww - p), e2 = __expf(k - p);
        bb = p + __logf(e1 + e2 + 1e-8f);
    }
    bc[tid] = bb;
}

__global__ __launch_bounds__(256) void wkv_p1(
    const float* __restrict__ bc, const float* __restrict__ wdec, float* __restrict__ bbin)
{
    const int gid = blockIdx.x * 256 + threadIdx.x;   // 0..8191 = b*C + c
    const int c = gid & (C - 1), b = gid >> 10;
    const float Lw = (float)LCH * wdec[c];
    float bb = -1e38f;
    #pragma unroll 8
    for (int j = 0; j < NCH; ++j) {
        const int idx = (b * NCH + j) * C + c;
        bbin[idx] = bb;
        const float a = Lw + bb;
        const float bcv = bc[idx];
        const float m = fmaxf(a, bcv);
        bb = m + __logf(__expf(a - m) + __expf(bcv - m));
    }
}

__global__ __launch_bounds__(256) void wkv_k2a(
    const u32* __restrict__ kvp, const float* __restrict__ wdec,
    const float* __restrict__ bbin, float* __restrict__ logS, float* __restrict__ Rr)
{
    const int tid = blockIdx.x * 256 + threadIdx.x;
    const int c = tid & (C - 1), ci = tid >> 10;
    const float w = wdec[c];
    const size_t L = ((size_t)(ci >> 6) * T + (size_t)(ci & (NCH - 1)) * LCH) * C + c;
    float bb = bbin[tid], ls = 0.0f, R = 0.0f;
    #pragma unroll 4
    for (int t = 0; t < LCH; ++t) {
        const u32 kv = kvp[L + (size_t)t * C];
        const float k = bf2f((u16)(kv & 0xffffu)), v = bf2f((u16)(kv >> 16));
        const float ww = w + bb;
        const float p = fmaxf(ww, k);
        const float e1 = __expf(ww - p), e2 = __expf(k - p);
        R = e1 * R + e2 * v;
        ls += ww - p;                       // log of alpha product (<=0)
        bb = p + __logf(e1 + e2 + 1e-8f);
    }
    logS[tid] = ls;
    Rr[tid] = R;
}

__global__ __launch_bounds__(256) void wkv_p2(
    const float* __restrict__ logS, const float* __restrict__ Rr, float* __restrict__ aain)
{
    const int gid = blockIdx.x * 256 + threadIdx.x;   // b*C + c
    const int c = gid & (C - 1), b = gid >> 10;
    float a = 0.0f;
    #pragma unroll 8
    for (int j = 0; j < NCH; ++j) {
        const int idx = (b * NCH + j) * C + c;
        aain[idx] = a;
        a = __expf(logS[idx]) * a + Rr[idx];
    }
}

__global__ __launch_bounds__(256) void wkv_k2c(
    const u32* __restrict__ kvp, const u16* __restrict__ rbuf, const float* __restrict__ x,
    const float* __restrict__ wdec, const float* __restrict__ ufirst,
    const float* __restrict__ bbin, const float* __restrict__ aain,
    float* __restrict__ x2, float* __restrict__ state)
{
    const int tid = blockIdx.x * 256 + threadIdx.x;
    const int c = tid & (C - 1), ci = tid >> 10;
    const int b = ci >> 6, j = ci & (NCH - 1);
    const float w = wdec[c], u = ufirst[c];
    float aa = aain[tid], bb = bbin[tid];
    const size_t L = ((size_t)b * T + (size_t)j * LCH) * C + c;
    #pragma unroll 4
    for (int t = 0; t < LCH; ++t) {
        const size_t idx = L + (size_t)t * C;
        const u32 kv = kvp[idx];
        const float k = bf2f((u16)(kv & 0xffffu)), v = bf2f((u16)(kv >> 16));
        const float r = bf2f(rbuf[idx]), xv = x[idx];
        float ww = u + k;
        float p  = fmaxf(bb, ww);
        float e1 = __expf(bb - p), e2 = __expf(ww - p);
        const float y = (e1 * aa + e2 * v) / (e1 + e2 + 1e-8f);
        x2[idx] = xv + r * y;
        ww = w + bb;
        p  = fmaxf(ww, k);
        e1 = __expf(ww - p); e2 = __expf(k - p);
        aa = e1 * aa + e2 * v;
        bb = p + __logf(e1 + e2 + 1e-8f);
    }
    if (j == NCH - 1) {
        state[2 * (b * C + c)]     = aa;
        state[2 * (b * C + c) + 1] = bb;
    }
}

// ---------------- LN2 + rr + xp_s snapshot ----------------
__global__ __launch_bounds__(256) void ln2_kernel(
    const float* __restrict__ x2, const float* __restrict__ g, const float* __restrict__ b,
    const float* __restrict__ cmr, u16* __restrict__ xn, u16* __restrict__ rr,
    u16* __restrict__ xps)
{
    const int row = blockIdx.x, tid = threadIdx.x;
    const size_t base = (size_t)row * C;
    const int t = row & (T - 1);
    const size_t basep = (size_t)(row - t + (t ? t - 1 : T - 1)) * C;   // cm xp row (wraps)
    const int c = tid * 4;
    float4 v = *(const float4*)&x2[base + c];
    float s  = v.x + v.y + v.z + v.w;
    float s2 = v.x*v.x + v.y*v.y + v.z*v.z + v.w*v.w;
    #pragma unroll
    for (int off = 32; off >= 1; off >>= 1) { s += __shfl_xor(s, off); s2 += __shfl_xor(s2, off); }
    __shared__ float red[8];
    const int wave = tid >> 6, lane = tid & 63;
    if (lane == 0) { red[wave] = s; red[4 + wave] = s2; }
    __syncthreads();
    const float sum  = red[0] + red[1] + red[2] + red[3];
    const float sums = red[4] + red[5] + red[6] + red[7];
    const float mean = sum * (1.0f / C);
    const float var  = sums * (1.0f / C) - mean * mean;
    const float rstd = rsqrtf(var + 1e-5f);
    float4 gv = *(const float4*)&g[c];
    float4 bv = *(const float4*)&b[c];
    float4 fv = *(const float4*)&cmr[c];
    float4 xp = *(const float4*)&x2[basep + c];
    float xn0 = (v.x - mean) * rstd * gv.x + bv.x;
    float xn1 = (v.y - mean) * rstd * gv.y + bv.y;
    float xn2 = (v.z - mean) * rstd * gv.z + bv.z;
    float xn3 = (v.w - mean) * rstd * gv.w + bv.w;
    u16x4 o; o.x = f2bf(xn0); o.y = f2bf(xn1); o.z = f2bf(xn2); o.w = f2bf(xn3);
    *(u16x4*)&xn[base + c] = o;
    u16x4 p4; p4.x = f2bf(xp.x); p4.y = f2bf(xp.y); p4.z = f2bf(xp.z); p4.w = f2bf(xp.w);
    *(u16x4*)&xps[base + c] = p4;
    u16x4 r4;
    r4.x = f2bf(sigmoidf_(xn0 * fv.x + xp.x * (1.0f - fv.x)));
    r4.y = f2bf(sigmoidf_(xn1 * fv.y + xp.y * (1.0f - fv.y)));
    r4.z = f2bf(sigmoidf_(xn2 * fv.z + xp.z * (1.0f - fv.z)));
    r4.w = f2bf(sigmoidf_(xn3 * fv.w + xp.w * (1.0f - fv.w)));
    *(u16x4*)&rr[base + c] = r4;
}

// ---------------- GEMM2 (one 2048-col half) + cm-mix + relu^2 -> h_half (bf16) ----------------
__global__ __launch_bounds__(512, 2) void gemm2_kernel(
    const u16* __restrict__ xn, const u16* __restrict__ wt,   // wt pre-offset to half
    const u16* __restrict__ xps, const float* __restrict__ cmk,
    u16* __restrict__ hbuf, const int nbase)
{
    __shared__ __align__(16) u16 lds[8 * 8192];
    f32x4 acc[2][2][4][2];
    const int nbn = 8;
    int id = blockIdx.x;
    id = (id & 7) * (512 >> 3) + (id >> 3);
    const int m0 = (id / nbn) << 8, n0 = (id % nbn) << 8;
    gemm256_mainloop(xn, C, wt, C, 16, m0, n0, lds, acc);

    const int tid = threadIdx.x, wave = tid >> 6, lane = tid & 63;
    const int q = lane >> 4, m16 = lane & 15;
    const int wm = wave >> 2, wn = wave & 3;
    #pragma unroll
    for (int a2 = 0; a2 < 2; ++a2)
    #pragma unroll
    for (int mf = 0; mf < 4; ++mf)
    #pragma unroll
    for (int rg = 0; rg < 4; ++rg) {
        const int row = m0 + a2 * 128 + wm * 64 + mf * 16 + q * 4 + rg;
        #pragma unroll
        for (int b2 = 0; b2 < 2; ++b2)
        #pragma unroll
        for (int nf = 0; nf < 2; ++nf) {
            const int nloc = n0 + b2 * 128 + wn * 32 + nf * 16 + m16;  // 0..2047
            const int cc = (nbase + nloc) & (C - 1);
            const float f = cmk[cc];
            const float xp = bf2f(xps[(size_t)row * C + cc]);
            const float kk = acc[a2][b2][mf][nf][rg] * f + xp * (1.0f - f);
            const float h = fmaxf(kk, 0.0f);
            hbuf[(size_t)row * 2048 + nloc] = f2bf(h * h);
        }
    }
}

// ---------------- GEMM3 (K=2048 half) + residual epilogue, accumulates into out ----------------
__global__ __launch_bounds__(512, 2) void gemm3_kernel(
    const u16* __restrict__ hbuf, const u16* __restrict__ wt,  // wt pre-offset to half
    const u16* __restrict__ rr, float* __restrict__ out)
{
    __shared__ __align__(16) u16 lds[8 * 8192];
    f32x4 acc[2][2][4][2];
    const int nbn = 4;
    int id = blockIdx.x;
    id = (id & 7) * (256 >> 3) + (id >> 3);
    const int m0 = (id / nbn) << 8, n0 = (id % nbn) << 8;
    gemm256_mainloop(hbuf, 2048, wt, 4096, 32, m0, n0, lds, acc);

    const int tid = threadIdx.x, wave = tid >> 6, lane = tid & 63;
    const int q = lane >> 4, m16 = lane & 15;
    const int wm = wave >> 2, wn = wave & 3;
    #pragma unroll
    for (int a2 = 0; a2 < 2; ++a2)
    #pragma unroll
    for (int mf = 0; mf < 4; ++mf)
    #pragma unroll
    for (int rg = 0; rg < 4; ++rg) {
        const int row = m0 + a2 * 128 + wm * 64 + mf * 16 + q * 4 + rg;
        #pragma unroll
        for (int b2 = 0; b2 < 2; ++b2)
        #pragma unroll
        for (int nf = 0; nf < 2; ++nf) {
            const int cc = n0 + b2 * 128 + wn * 32 + nf * 16 + m16;
            const size_t idx = (size_t)row * C + cc;
            const float base = out[idx];   // pass0: x2; pass1: partial result
            out[idx] = base + bf2f(rr[idx]) * acc[a2][b2][mf][nf][rg];
        }
    }
}

// ---------------- workspace layout (byte offsets), total 176 MB ----------------
#define OFF_WT_CM  0            //  8 MB  (4096 x 1024 bf16)
#define OFF_WT_CP  8388608      //  8 MB  (1024 x 4096 bf16)
#define OFF_XN     16777216     // 32 MB  (M x C bf16; LN1 then LN2)
#define OFF_KV     50331648     // 64 MB  (M x C packed (k,v) bf16 pairs)
#define OFF_H      OFF_KV       // 64 MB  (M x 2048 bf16 half; overlays kv, dead after wkv)
#define OFF_RB     117440512    // 32 MB  (bf16; reused as rr after wkv)
#define OFF_WT_TM  150994944    //  6 MB  (3072 x 1024 bf16; dead after gemm1)
// wkv scratch overlays the wt_tm/xps extent during the scan (dead then):
#define OFF_BC     150994944    // 2 MB
#define OFF_BBIN   153092096    // 2 MB
#define OFF_LOGS   155189248    // 2 MB
#define OFF_RCH    157286400    // 2 MB
#define OFF_AAIN   159383552    // 2 MB
#define OFF_XPS    150994944    // 32 MB (bf16 shifted x2; born at ln2, after wkv)

extern "C" void kernel_launch(void* const* d_in, const int* in_sizes, int n_in,
                              void* d_out, int out_size, void* d_ws, size_t ws_size,
                              hipStream_t stream) {
    const float* x          = (const float*)d_in[0];
    const float* time_decay = (const float*)d_in[1];
    const float* time_first = (const float*)d_in[2];
    const float* W_tm       = (const float*)d_in[3];
    const float* g1         = (const float*)d_in[4];
    const float* b1         = (const float*)d_in[5];
    const float* tmk        = (const float*)d_in[6];
    const float* tmv        = (const float*)d_in[7];
    const float* tmr        = (const float*)d_in[8];
    const float* W_cm       = (const float*)d_in[9];
    const float* W_cp       = (const float*)d_in[10];
    const float* g2         = (const float*)d_in[11];
    const float* b2         = (const float*)d_in[12];
    const float* cmk        = (const float*)d_in[13];
    const float* cmr        = (const float*)d_in[14];
    float* out = (float*)d_out;

    char* ws = (char*)d_ws;
    u16*   wt_cm = (u16*)(ws + OFF_WT_CM);
    u16*   wt_cp = (u16*)(ws + OFF_WT_CP);
    u16*   xn    = (u16*)(ws + OFF_XN);
    u16*   kvbuf = (u16*)(ws + OFF_KV);
    u16*   hbuf  = (u16*)(ws + OFF_H);
    u16*   rbuf  = (u16*)(ws + OFF_RB);   // rr reuses this after wkv
    u16*   wt_tm = (u16*)(ws + OFF_WT_TM);
    u16*   xps   = (u16*)(ws + OFF_XPS);
    float* bc    = (float*)(ws + OFF_BC);
    float* bbin  = (float*)(ws + OFF_BBIN);
    float* logS  = (float*)(ws + OFF_LOGS);
    float* Rch   = (float*)(ws + OFF_RCH);
    float* aain  = (float*)(ws + OFF_AAIN);
    float* x2    = out;                    // residual stream lives in d_out

    // 1. weights -> bf16 B^T
    transpose_cast_kernel<<<dim3(1024/32, 3072/32), dim3(32, 8), 0, stream>>>(W_tm, wt_tm, 1024, 3072);
    transpose_cast_kernel<<<dim3(1024/32, 4096/32), dim3(32, 8), 0, stream>>>(W_cm, wt_cm, 1024, 4096);
    transpose_cast_kernel<<<dim3(4096/32, 1024/32), dim3(32, 8), 0, stream>>>(W_cp, wt_cp, 4096, 1024);
    // 2. LN1
    ln1_kernel<<<M, 256, 0, stream>>>(x, g1, b1, xn);
    // 3. GEMM1 + time-mix (256^2 8-phase; 768 blocks)
    gemm1_kernel<<<768, 512, 0, stream>>>(xn, wt_tm, x, tmk, tmv, tmr, kvbuf, rbuf);
    // 4. WKV chunked parallel scan (x2 -> d_out body, state -> d_out tail)
    {
        const u32* kvp = (const u32*)kvbuf;
        wkv_k1 <<<WKV_THREADS/256, 256, 0, stream>>>(kvp, time_decay, bc);
        wkv_p1 <<<(Bb*C)/256, 256, 0, stream>>>(bc, time_decay, bbin);
        wkv_k2a<<<WKV_THREADS/256, 256, 0, stream>>>(kvp, time_decay, bbin, logS, Rch);
        wkv_p2 <<<(Bb*C)/256, 256, 0, stream>>>(logS, Rch, aain);
        wkv_k2c<<<WKV_THREADS/256, 256, 0, stream>>>(kvp, rbuf, x, time_decay, time_first,
                                                     bbin, aain, x2, out + (size_t)M * C);
    }
    // 5. LN2 + rr + xp snapshot
    ln2_kernel<<<M, 256, 0, stream>>>(x2, g2, b2, cmr, xn, rbuf, xps);
    // 6+7. channel-mix GEMMs in two hidden-halves (h_half overlays dead kv)
    for (int half = 0; half < 2; ++half) {
        const int nbase = half * 2048;
        gemm2_kernel<<<512, 512, 0, stream>>>(
            xn, wt_cm + (size_t)nbase * C, xps, cmk, hbuf, nbase);
        gemm3_kernel<<<256, 512, 0, stream>>>(
            hbuf, wt_cp + nbase, rbuf, out);
    }
}

// Round 4
// 845.614 us; speedup vs baseline: 1.1367x; 1.0205x over previous
//
#include <hip/hip_runtime.h>

// RWKV block on MI355X (gfx950).  B=8, T=2048, C=1024, M=16384.
// R7: loosened the counted-vmcnt schedule.  R6 passed but ran at ~2800
//     cy/phase (gemm1 225us, MfmaUtil 19%, nothing busy => stall-bound):
//     its vmcnt(4) waits had only a 2-phase lag to the stage they drain,
//     ~= HBM latency, so every wait stalled and paced the barrier-locked
//     phases.  New stagger gives every stage >=5 phases before first read
//     and every wait a >=3-phase lag:
//       stages: p0:b1B1(t+1) p1:b1A1(t+1) p2:b0A0(t+2) p3:b0B0 p4:b0B1
//               p5:b0A1 p6:b1A0(t+3) p7:b1B0(t+3)
//       waits:  end-p1 vmcnt(8), end-p3 vmcnt(8), end-p4 vmcnt(6),
//               end-p7 vmcnt(6)   (lags 4,4,3,3 phases)
//     Stage-id audit (iter i, stage ids 6+8i+p+1, 2 loads each):
//       p0 reads b0A0(8i+1),b0B0(8i+2): end-p7[i-1] lands <=8i+3  OK
//       p2 reads b0A1(8i+4): end-p1 lands <=8i+4                  OK
//       p4 reads b1A0(8i+5),b1B0(8i+6): end-p3 lands <=8i+6       OK
//       p5 reads b1B1(8i+7): end-p4 lands <=8i+8                  OK
//       p6 reads b1A1(8i+8): end-p4                               OK
//     No phase stages a half it reads; every overwrite >=1 barrier after
//     the old contents' last read.
// R5/R6: 256^2 8-phase schedule, BK=64, 8 waves (2Mx4N), 128 KiB LDS
//     double-buffer, raw s_barrier, setprio around MFMA, XOR-chunk LDS
//     swizzle (bank-conflict-free).  WKV: chunked parallel scan (R3).

#define Bb 8
#define T 2048
#define C 1024
#define M (Bb*T)
#define LCH 32            // chunk length
#define NCH 64            // chunks per sequence (T/LCH)
#define NCI (Bb*NCH)      // 512 chunk instances
#define WKV_THREADS (NCI*C)   // 524288

typedef unsigned short u16;
typedef unsigned int u32;
typedef __bf16 bf16x8 __attribute__((ext_vector_type(8)));
typedef float f32x4 __attribute__((ext_vector_type(4)));
typedef u16 u16x4 __attribute__((ext_vector_type(4)));

__device__ __forceinline__ u16 f2bf(float f) {
    u32 u = __float_as_uint(f);
    u32 r = u + 0x7FFFu + ((u >> 16) & 1u);   // round-to-nearest-even
    return (u16)(r >> 16);
}
__device__ __forceinline__ float bf2f(u16 s) {
    return __uint_as_float(((u32)s) << 16);
}
__device__ __forceinline__ float sigmoidf_(float z) {
    return 1.0f / (1.0f + __expf(-z));
}
__device__ __forceinline__ void load_lds16(const void* g, void* l) {
    __builtin_amdgcn_global_load_lds(
        (const __attribute__((address_space(1))) void*)g,
        (__attribute__((address_space(3))) void*)l, 16, 0, 0);
}

// ---------------- weight transpose + cast: Wt[n][k] = bf16(W[k][n]) ----------------
__global__ __launch_bounds__(256) void transpose_cast_kernel(
    const float* __restrict__ W, u16* __restrict__ Wt, int K, int N)
{
    __shared__ float tile[32][33];
    const int bk = blockIdx.x * 32, bn = blockIdx.y * 32;
    const int tx = threadIdx.x, ty = threadIdx.y;   // (32,8)
    #pragma unroll
    for (int i = 0; i < 32; i += 8)
        tile[ty + i][tx] = W[(size_t)(bk + ty + i) * N + bn + tx];
    __syncthreads();
    #pragma unroll
    for (int i = 0; i < 32; i += 8)
        Wt[(size_t)(bn + ty + i) * K + bk + tx] = f2bf(tile[tx][ty + i]);
}

// ============ 256^2 8-phase GEMM mainloop (T2+T3+T4+T5) ============
// A (lda-major), Bt (ldb-major), bf16 row-major.  nkt = K/64 (even, pow2).
// LDS: 8 slots of 16 KiB: slot = buf*4 + mat*2 + half (A: slots 0,1; B: 2,3).
// Half-tile = 128 rows x 64 k, rows swizzled: row r chunk c holds global
// chunk c^(r&7) (chunk = 16B).  Staged linearly (dst = tid*16 / +8192).
// Per wave (wm=wave>>2, wn=wave&3): quadrant (a,b) covers
// rows a*128 + wm*64 + [0,64), cols b*128 + wn*32 + [0,32).
// Phase pp in 0..3 computes quadrant (pp>>1, pp&1) of K-tile buf=p>>2.
__device__ __forceinline__ void gemm256_mainloop(
    const u16* __restrict__ A, const int lda,
    const u16* __restrict__ Bt, const int ldb, const int nkt,
    const int m0, const int n0, u16* lds, f32x4 acc[2][2][4][2])
{
    const int tid  = threadIdx.x;
    const int wave = tid >> 6, lane = tid & 63;
    const int q = lane >> 4, m16 = lane & 15;
    const int wm = wave >> 2, wn = wave & 3;

    const f32x4 zero4 = {0.f, 0.f, 0.f, 0.f};
    #pragma unroll
    for (int i = 0; i < 2; ++i)
        #pragma unroll
        for (int j = 0; j < 2; ++j)
            #pragma unroll
            for (int k = 0; k < 4; ++k)
                #pragma unroll
                for (int l = 0; l < 2; ++l) acc[i][j][k][l] = zero4;

    // staging geometry: thread covers (row sr, chunk tid&7) and (+64 rows)
    const int sr = tid >> 3;                              // 0..63
    const int kc = ((tid & 7) ^ (sr & 7)) << 3;           // swizzled src chunk (shorts)
    const size_t abase = (size_t)(m0 + sr) * lda + kc;
    const size_t bbase = (size_t)(n0 + sr) * ldb + kc;
    const size_t lda64 = (size_t)lda << 6, ldb64 = (size_t)ldb << 6;
    char* ldsb = (char*)lds;
    const int dst0 = tid << 4;

#define STG_A(bufs, hf, k0) do { \
    char* d_ = ldsb + (((bufs) * 4 + (hf)) << 14) + dst0; \
    const u16* g_ = A + abase + (size_t)(hf) * 2 * lda64 + (k0); \
    load_lds16(g_, d_); load_lds16(g_ + lda64, d_ + 8192); } while (0)
#define STG_B(bufs, hf, k0) do { \
    char* d_ = ldsb + (((bufs) * 4 + 2 + (hf)) << 14) + dst0; \
    const u16* g_ = Bt + bbase + (size_t)(hf) * 2 * ldb64 + (k0); \
    load_lds16(g_, d_); load_lds16(g_ + ldb64, d_ + 8192); } while (0)

    // prologue: b0A0,b0B0,b0B1,b0A1 (tile0), b1A0,b1B0 (tile1); 12 loads.
    // vmcnt(6) -> first 3 stages (A0,B0,B1) landed, covering p0/p1 reads;
    // b0A1 covered by end-p1 wait, b1A0/B0 by end-p3 wait.
    STG_A(0, 0, 0);  STG_B(0, 0, 0);  STG_B(0, 1, 0);  STG_A(0, 1, 0);
    STG_A(1, 0, 64); STG_B(1, 0, 64);
    asm volatile("s_waitcnt vmcnt(6)" ::: "memory");
    __builtin_amdgcn_s_barrier();

    const int arow = ((wm << 6) + m16) << 6;   // shorts within half-tile
    const int brow = ((wn << 5) + m16) << 6;
    const int xh = m16 & 7;
    const int ch0 = (q ^ xh) << 3, ch1 = ((4 + q) ^ xh) << 3;

    #pragma unroll 1
    for (int kt2 = 0; kt2 < nkt; kt2 += 2) {
        #pragma unroll
        for (int p = 0; p < 8; ++p) {
            const int pp = p & 3, aa = pp >> 1, bbq = pp & 1, buf = p >> 2;
            const u16* Ap = lds + ((buf * 4 + aa) << 13) + arow;
            const u16* Bq = lds + ((buf * 4 + 2 + bbq) << 13) + brow;
            bf16x8 av[4][2], bv[2][2];
            #pragma unroll
            for (int mf = 0; mf < 4; ++mf) {
                av[mf][0] = *(const bf16x8*)&Ap[mf * 1024 + ch0];
                av[mf][1] = *(const bf16x8*)&Ap[mf * 1024 + ch1];
            }
            #pragma unroll
            for (int nf = 0; nf < 2; ++nf) {
                bv[nf][0] = *(const bf16x8*)&Bq[nf * 1024 + ch0];
                bv[nf][1] = *(const bf16x8*)&Bq[nf * 1024 + ch1];
            }
            // stage stagger: >=5 phases before first read, >=1 barrier after
            // the overwritten contents' last read (k wraps in tail; unused)
            {
                const int k1 = ((kt2 + 1) & (nkt - 1)) << 6;
                const int k2 = ((kt2 + 2) & (nkt - 1)) << 6;
                const int k3 = ((kt2 + 3) & (nkt - 1)) << 6;
                if (p == 0)      STG_B(1, 1, k1);   // b1B1 <- t+1
                else if (p == 1) STG_A(1, 1, k1);   // b1A1 <- t+1
                else if (p == 2) STG_A(0, 0, k2);   // b0A0 <- t+2
                else if (p == 3) STG_B(0, 0, k2);   // b0B0 <- t+2
                else if (p == 4) STG_B(0, 1, k2);   // b0B1 <- t+2
                else if (p == 5) STG_A(0, 1, k2);   // b0A1 <- t+2
                else if (p == 6) STG_A(1, 0, k3);   // b1A0 <- t+3
                else             STG_B(1, 0, k3);   // b1B0 <- t+3
            }
            __builtin_amdgcn_s_barrier();
            asm volatile("s_waitcnt lgkmcnt(0)" ::: "memory");
            __builtin_amdgcn_s_setprio(1);
            #pragma unroll
            for (int mf = 0; mf < 4; ++mf)
                #pragma unroll
                for (int nf = 0; nf < 2; ++nf) {
                    acc[aa][bbq][mf][nf] = __builtin_amdgcn_mfma_f32_16x16x32_bf16(
                        av[mf][0], bv[nf][0], acc[aa][bbq][mf][nf], 0, 0, 0);
                    acc[aa][bbq][mf][nf] = __builtin_amdgcn_mfma_f32_16x16x32_bf16(
                        av[mf][1], bv[nf][1], acc[aa][bbq][mf][nf], 0, 0, 0);
                }
            __builtin_amdgcn_s_setprio(0);
            // counted waits, all with >=3-phase lag to the stage they drain
            if (p == 1)      asm volatile("s_waitcnt vmcnt(8)" ::: "memory");
            else if (p == 3) asm volatile("s_waitcnt vmcnt(8)" ::: "memory");
            else if (p == 4) asm volatile("s_waitcnt vmcnt(6)" ::: "memory");
            else if (p == 7) asm volatile("s_waitcnt vmcnt(6)" ::: "memory");
            __builtin_amdgcn_s_barrier();
        }
    }
    // drain DMA before LDS dealloc / epilogue
    asm volatile("s_waitcnt vmcnt(0)" ::: "memory");
#undef STG_A
#undef STG_B
}

// ---------------- LN1: xn = LN(x,g1,b1) as bf16 ----------------
__global__ __launch_bounds__(256) void ln1_kernel(
    const float* __restrict__ x, const float* __restrict__ g, const float* __restrict__ b,
    u16* __restrict__ xn)
{
    const int row = blockIdx.x, tid = threadIdx.x;
    const size_t base = (size_t)row * C;
    const int c = tid * 4;
    float4 v = *(const float4*)&x[base + c];
    float s  = v.x + v.y + v.z + v.w;
    float s2 = v.x*v.x + v.y*v.y + v.z*v.z + v.w*v.w;
    #pragma unroll
    for (int off = 32; off >= 1; off >>= 1) { s += __shfl_xor(s, off); s2 += __shfl_xor(s2, off); }
    __shared__ float red[8];
    const int wave = tid >> 6, lane = tid & 63;
    if (lane == 0) { red[wave] = s; red[4 + wave] = s2; }
    __syncthreads();
    const float sum  = red[0] + red[1] + red[2] + red[3];
    const float sums = red[4] + red[5] + red[6] + red[7];
    const float mean = sum * (1.0f / C);
    const float var  = sums * (1.0f / C) - mean * mean;
    const float rstd = rsqrtf(var + 1e-5f);
    float4 gv = *(const float4*)&g[c];
    float4 bv = *(const float4*)&b[c];
    u16x4 o;
    o.x = f2bf((v.x - mean) * rstd * gv.x + bv.x);
    o.y = f2bf((v.y - mean) * rstd * gv.y + bv.y);
    o.z = f2bf((v.z - mean) * rstd * gv.z + bv.z);
    o.w = f2bf((v.w - mean) * rstd * gv.w + bv.w);
    *(u16x4*)&xn[base + c] = o;
}

// ---------------- GEMM1 + time-mix epilogue -> packed kv (dword) + r (bf16) ----------------
__global__ __launch_bounds__(512, 2) void gemm1_kernel(
    const u16* __restrict__ xn, const u16* __restrict__ wt,
    const float* __restrict__ x,
    const float* __restrict__ tmk, const float* __restrict__ tmv, const float* __restrict__ tmr,
    u16* __restrict__ kvbuf, u16* __restrict__ rbuf)
{
    __shared__ __align__(16) u16 lds[8 * 8192];   // 128 KiB
    f32x4 acc[2][2][4][2];
    const int nbn = 12;
    int id = blockIdx.x;
    id = (id & 7) * (768 >> 3) + (id >> 3);       // XCD-aware swizzle (768 % 8 == 0)
    const int m0 = (id / nbn) << 8, n0 = (id % nbn) << 8;
    gemm256_mainloop(xn, C, wt, C, 16, m0, n0, lds, acc);

    const int tid = threadIdx.x, wave = tid >> 6, lane = tid & 63;
    const int q = lane >> 4, m16 = lane & 15;
    const int wm = wave >> 2, wn = wave & 3;
    const int grp = n0 >> 10;                     // 0=k, 1=v, 2=r (uniform per block)
    #pragma unroll
    for (int a2 = 0; a2 < 2; ++a2)
    #pragma unroll
    for (int mf = 0; mf < 4; ++mf)
    #pragma unroll
    for (int rg = 0; rg < 4; ++rg) {
        const int row = m0 + a2 * 128 + wm * 64 + mf * 16 + q * 4 + rg;
        const int t = row & (T - 1);
        const size_t rowp = (size_t)(t ? row - 1 : row) * C;   // time-mix x_prev row
        #pragma unroll
        for (int b2 = 0; b2 < 2; ++b2)
        #pragma unroll
        for (int nf = 0; nf < 2; ++nf) {
            const int cc = (n0 + b2 * 128 + wn * 32 + nf * 16 + m16) & (C - 1);
            const float val = acc[a2][b2][mf][nf][rg];
            const float xp = x[rowp + cc];
            if (grp == 0) {
                const float f = tmk[cc];
                kvbuf[(size_t)row * 2048 + 2 * cc] = f2bf(val * f + xp * (1.0f - f));
            } else if (grp == 1) {
                const float f = tmv[cc];
                kvbuf[(size_t)row * 2048 + 2 * cc + 1] = f2bf(val * f + xp * (1.0f - f));
            } else {
                const float f = tmr[cc];
                rbuf[(size_t)row * C + cc] = f2bf(sigmoidf_(val * f + xp * (1.0f - f)));
            }
        }
    }
}

// ================= WKV chunked parallel scan =================
__global__ __launch_bounds__(256) void wkv_k1(
    const u32* __restrict__ kvp, const float* __restrict__ wdec, float* __restrict__ bc)
{
    const int tid = blockIdx.x * 256 + threadIdx.x;
    const int c = tid & (C - 1), ci = tid >> 10;
    const float w = wdec[c];
    const size_t L = ((size_t)(ci >> 6) * T + (size_t)(ci & (NCH - 1)) * LCH) * C + c;
    float bb = -1e38f;
    #pragma unroll 4
    for (int t = 0; t < LCH; ++t) {
        const float k = bf2f((u16)(kvp[L + (size_t)t * C] & 0xffffu));
        const float ww = w + bb;
        const float p = fmaxf(ww, k);
        const float e1 = __expf(ww - p), e2 = __expf(k - p);
        bb = p + __logf(e1 + e2 + 1e-8f);
    }
    bc[tid] = bb;
}

__global__ __launch_bounds__(256) void wkv_p1(
    const float* __restrict__ bc, const float* __restrict__ wdec, float* __restrict__ bbin)
{
    const int gid = blockIdx.x * 256 + threadIdx.x;   // 0..8191 = b*C + c
    const int c = gid & (C - 1), b = gid >> 10;
    const float Lw = (float)LCH * wdec[c];
    float bb = -1e38f;
    #pragma unroll 8
    for (int j = 0; j < NCH; ++j) {
        const int idx = (b * NCH + j) * C + c;
        bbin[idx] = bb;
        const float a = Lw + bb;
        const float bcv = bc[idx];
        const float m = fmaxf(a, bcv);
        bb = m + __logf(__expf(a - m) + __expf(bcv - m));
    }
}

__global__ __launch_bounds__(256) void wkv_k2a(
    const u32* __restrict__ kvp, const float* __restrict__ wdec,
    const float* __restrict__ bbin, float* __restrict__ logS, float* __restrict__ Rr)
{
    const int tid = blockIdx.x * 256 + threadIdx.x;
    const int c = tid & (C - 1), ci = tid >> 10;
    const float w = wdec[c];
    const size_t L = ((size_t)(ci >> 6) * T + (size_t)(ci & (NCH - 1)) * LCH) * C + c;
    float bb = bbin[tid], ls = 0.0f, R = 0.0f;
    #pragma unroll 4
    for (int t = 0; t < LCH; ++t) {
        const u32 kv = kvp[L + (size_t)t * C];
        const float k = bf2f((u16)(kv & 0xffffu)), v = bf2f((u16)(kv >> 16));
        const float ww = w + bb;
        const float p = fmaxf(ww, k);
        const float e1 = __expf(ww - p), e2 = __expf(k - p);
        R = e1 * R + e2 * v;
        ls += ww - p;                       // log of alpha product (<=0)
        bb = p + __logf(e1 + e2 + 1e-8f);
    }
    logS[tid] = ls;
    Rr[tid] = R;
}

__global__ __launch_bounds__(256) void wkv_p2(
    const float* __restrict__ logS, const float* __restrict__ Rr, float* __restrict__ aain)
{
    const int gid = blockIdx.x * 256 + threadIdx.x;   // b*C + c
    const int c = gid & (C - 1), b = gid >> 10;
    float a = 0.0f;
    #pragma unroll 8
    for (int j = 0; j < NCH; ++j) {
        const int idx = (b * NCH + j) * C + c;
        aain[idx] = a;
        a = __expf(logS[idx]) * a + Rr[idx];
    }
}

__global__ __launch_bounds__(256) void wkv_k2c(
    const u32* __restrict__ kvp, const u16* __restrict__ rbuf, const float* __restrict__ x,
    const float* __restrict__ wdec, const float* __restrict__ ufirst,
    const float* __restrict__ bbin, const float* __restrict__ aain,
    float* __restrict__ x2, float* __restrict__ state)
{
    const int tid = blockIdx.x * 256 + threadIdx.x;
    const int c = tid & (C - 1), ci = tid >> 10;
    const int b = ci >> 6, j = ci & (NCH - 1);
    const float w = wdec[c], u = ufirst[c];
    float aa = aain[tid], bb = bbin[tid];
    const size_t L = ((size_t)b * T + (size_t)j * LCH) * C + c;
    #pragma unroll 4
    for (int t = 0; t < LCH; ++t) {
        const size_t idx = L + (size_t)t * C;
        const u32 kv = kvp[idx];
        const float k = bf2f((u16)(kv & 0xffffu)), v = bf2f((u16)(kv >> 16));
        const float r = bf2f(rbuf[idx]), xv = x[idx];
        float ww = u + k;
        float p  = fmaxf(bb, ww);
        float e1 = __expf(bb - p), e2 = __expf(ww - p);
        const float y = (e1 * aa + e2 * v) / (e1 + e2 + 1e-8f);
        x2[idx] = xv + r * y;
        ww = w + bb;
        p  = fmaxf(ww, k);
        e1 = __expf(ww - p); e2 = __expf(k - p);
        aa = e1 * aa + e2 * v;
        bb = p + __logf(e1 + e2 + 1e-8f);
    }
    if (j == NCH - 1) {
        state[2 * (b * C + c)]     = aa;
        state[2 * (b * C + c) + 1] = bb;
    }
}

// ---------------- LN2 + rr + xp_s snapshot ----------------
__global__ __launch_bounds__(256) void ln2_kernel(
    const float* __restrict__ x2, const float* __restrict__ g, const float* __restrict__ b,
    const float* __restrict__ cmr, u16* __restrict__ xn, u16* __restrict__ rr,
    u16* __restrict__ xps)
{
    const int row = blockIdx.x, tid = threadIdx.x;
    const size_t base = (size_t)row * C;
    const int t = row & (T - 1);
    const size_t basep = (size_t)(row - t + (t ? t - 1 : T - 1)) * C;   // cm xp row (wraps)
    const int c = tid * 4;
    float4 v = *(const float4*)&x2[base + c];
    float s  = v.x + v.y + v.z + v.w;
    float s2 = v.x*v.x + v.y*v.y + v.z*v.z + v.w*v.w;
    #pragma unroll
    for (int off = 32; off >= 1; off >>= 1) { s += __shfl_xor(s, off); s2 += __shfl_xor(s2, off); }
    __shared__ float red[8];
    const int wave = tid >> 6, lane = tid & 63;
    if (lane == 0) { red[wave] = s; red[4 + wave] = s2; }
    __syncthreads();
    const float sum  = red[0] + red[1] + red[2] + red[3];
    const float sums = red[4] + red[5] + red[6] + red[7];
    const float mean = sum * (1.0f / C);
    const float var  = sums * (1.0f / C) - mean * mean;
    const float rstd = rsqrtf(var + 1e-5f);
    float4 gv = *(const float4*)&g[c];
    float4 bv = *(const float4*)&b[c];
    float4 fv = *(const float4*)&cmr[c];
    float4 xp = *(const float4*)&x2[basep + c];
    float xn0 = (v.x - mean) * rstd * gv.x + bv.x;
    float xn1 = (v.y - mean) * rstd * gv.y + bv.y;
    float xn2 = (v.z - mean) * rstd * gv.z + bv.z;
    float xn3 = (v.w - mean) * rstd * gv.w + bv.w;
    u16x4 o; o.x = f2bf(xn0); o.y = f2bf(xn1); o.z = f2bf(xn2); o.w = f2bf(xn3);
    *(u16x4*)&xn[base + c] = o;
    u16x4 p4; p4.x = f2bf(xp.x); p4.y = f2bf(xp.y); p4.z = f2bf(xp.z); p4.w = f2bf(xp.w);
    *(u16x4*)&xps[base + c] = p4;
    u16x4 r4;
    r4.x = f2bf(sigmoidf_(xn0 * fv.x + xp.x * (1.0f - fv.x)));
    r4.y = f2bf(sigmoidf_(xn1 * fv.y + xp.y * (1.0f - fv.y)));
    r4.z = f2bf(sigmoidf_(xn2 * fv.z + xp.z * (1.0f - fv.z)));
    r4.w = f2bf(sigmoidf_(xn3 * fv.w + xp.w * (1.0f - fv.w)));
    *(u16x4*)&rr[base + c] = r4;
}

// ---------------- GEMM2 (one 2048-col half) + cm-mix + relu^2 -> h_half (bf16) ----------------
__global__ __launch_bounds__(512, 2) void gemm2_kernel(
    const u16* __restrict__ xn, const u16* __restrict__ wt,   // wt pre-offset to half
    const u16* __restrict__ xps, const float* __restrict__ cmk,
    u16* __restrict__ hbuf, const int nbase)
{
    __shared__ __align__(16) u16 lds[8 * 8192];
    f32x4 acc[2][2][4][2];
    const int nbn = 8;
    int id = blockIdx.x;
    id = (id & 7) * (512 >> 3) + (id >> 3);
    const int m0 = (id / nbn) << 8, n0 = (id % nbn) << 8;
    gemm256_mainloop(xn, C, wt, C, 16, m0, n0, lds, acc);

    const int tid = threadIdx.x, wave = tid >> 6, lane = tid & 63;
    const int q = lane >> 4, m16 = lane & 15;
    const int wm = wave >> 2, wn = wave & 3;
    #pragma unroll
    for (int a2 = 0; a2 < 2; ++a2)
    #pragma unroll
    for (int mf = 0; mf < 4; ++mf)
    #pragma unroll
    for (int rg = 0; rg < 4; ++rg) {
        const int row = m0 + a2 * 128 + wm * 64 + mf * 16 + q * 4 + rg;
        #pragma unroll
        for (int b2 = 0; b2 < 2; ++b2)
        #pragma unroll
        for (int nf = 0; nf < 2; ++nf) {
            const int nloc = n0 + b2 * 128 + wn * 32 + nf * 16 + m16;  // 0..2047
            const int cc = (nbase + nloc) & (C - 1);
            const float f = cmk[cc];
            const float xp = bf2f(xps[(size_t)row * C + cc]);
            const float kk = acc[a2][b2][mf][nf][rg] * f + xp * (1.0f - f);
            const float h = fmaxf(kk, 0.0f);
            hbuf[(size_t)row * 2048 + nloc] = f2bf(h * h);
        }
    }
}

// ---------------- GEMM3 (K=2048 half) + residual epilogue, accumulates into out ----------------
__global__ __launch_bounds__(512, 2) void gemm3_kernel(
    const u16* __restrict__ hbuf, const u16* __restrict__ wt,  // wt pre-offset to half
    const u16* __restrict__ rr, float* __restrict__ out)
{
    __shared__ __align__(16) u16 lds[8 * 8192];
    f32x4 acc[2][2][4][2];
    const int nbn = 4;
    int id = blockIdx.x;
    id = (id & 7) * (256 >> 3) + (id >> 3);
    const int m0 = (id / nbn) << 8, n0 = (id % nbn) << 8;
    gemm256_mainloop(hbuf, 2048, wt, 4096, 32, m0, n0, lds, acc);

    const int tid = threadIdx.x, wave = tid >> 6, lane = tid & 63;
    const int q = lane >> 4, m16 = lane & 15;
    const int wm = wave >> 2, wn = wave & 3;
    #pragma unroll
    for (int a2 = 0; a2 < 2; ++a2)
    #pragma unroll
    for (int mf = 0; mf < 4; ++mf)
    #pragma unroll
    for (int rg = 0; rg < 4; ++rg) {
        const int row = m0 + a2 * 128 + wm * 64 + mf * 16 + q * 4 + rg;
        #pragma unroll
        for (int b2 = 0; b2 < 2; ++b2)
        #pragma unroll
        for (int nf = 0; nf < 2; ++nf) {
            const int cc = n0 + b2 * 128 + wn * 32 + nf * 16 + m16;
            const size_t idx = (size_t)row * C + cc;
            const float base = out[idx];   // pass0: x2; pass1: partial result
            out[idx] = base + bf2f(rr[idx]) * acc[a2][b2][mf][nf][rg];
        }
    }
}

// ---------------- workspace layout (byte offsets), total 176 MB ----------------
#define OFF_WT_CM  0            //  8 MB  (4096 x 1024 bf16)
#define OFF_WT_CP  8388608      //  8 MB  (1024 x 4096 bf16)
#define OFF_XN     16777216     // 32 MB  (M x C bf16; LN1 then LN2)
#define OFF_KV     50331648     // 64 MB  (M x C packed (k,v) bf16 pairs)
#define OFF_H      OFF_KV       // 64 MB  (M x 2048 bf16 half; overlays kv, dead after wkv)
#define OFF_RB     117440512    // 32 MB  (bf16; reused as rr after wkv)
#define OFF_WT_TM  150994944    //  6 MB  (3072 x 1024 bf16; dead after gemm1)
// wkv scratch overlays the wt_tm/xps extent during the scan (dead then):
#define OFF_BC     150994944    // 2 MB
#define OFF_BBIN   153092096    // 2 MB
#define OFF_LOGS   155189248    // 2 MB
#define OFF_RCH    157286400    // 2 MB
#define OFF_AAIN   159383552    // 2 MB
#define OFF_XPS    150994944    // 32 MB (bf16 shifted x2; born at ln2, after wkv)

extern "C" void kernel_launch(void* const* d_in, const int* in_sizes, int n_in,
                              void* d_out, int out_size, void* d_ws, size_t ws_size,
                              hipStream_t stream) {
    const float* x          = (const float*)d_in[0];
    const float* time_decay = (const float*)d_in[1];
    const float* time_first = (const float*)d_in[2];
    const float* W_tm       = (const float*)d_in[3];
    const float* g1         = (const float*)d_in[4];
    const float* b1         = (const float*)d_in[5];
    const float* tmk        = (const float*)d_in[6];
    const float* tmv        = (const float*)d_in[7];
    const float* tmr        = (const float*)d_in[8];
    const float* W_cm       = (const float*)d_in[9];
    const float* W_cp       = (const float*)d_in[10];
    const float* g2         = (const float*)d_in[11];
    const float* b2         = (const float*)d_in[12];
    const float* cmk        = (const float*)d_in[13];
    const float* cmr        = (const float*)d_in[14];
    float* out = (float*)d_out;

    char* ws = (char*)d_ws;
    u16*   wt_cm = (u16*)(ws + OFF_WT_CM);
    u16*   wt_cp = (u16*)(ws + OFF_WT_CP);
    u16*   xn    = (u16*)(ws + OFF_XN);
    u16*   kvbuf = (u16*)(ws + OFF_KV);
    u16*   hbuf  = (u16*)(ws + OFF_H);
    u16*   rbuf  = (u16*)(ws + OFF_RB);   // rr reuses this after wkv
    u16*   wt_tm = (u16*)(ws + OFF_WT_TM);
    u16*   xps   = (u16*)(ws + OFF_XPS);
    float* bc    = (float*)(ws + OFF_BC);
    float* bbin  = (float*)(ws + OFF_BBIN);
    float* logS  = (float*)(ws + OFF_LOGS);
    float* Rch   = (float*)(ws + OFF_RCH);
    float* aain  = (float*)(ws + OFF_AAIN);
    float* x2    = out;                    // residual stream lives in d_out

    // 1. weights -> bf16 B^T
    transpose_cast_kernel<<<dim3(1024/32, 3072/32), dim3(32, 8), 0, stream>>>(W_tm, wt_tm, 1024, 3072);
    transpose_cast_kernel<<<dim3(1024/32, 4096/32), dim3(32, 8), 0, stream>>>(W_cm, wt_cm, 1024, 4096);
    transpose_cast_kernel<<<dim3(4096/32, 1024/32), dim3(32, 8), 0, stream>>>(W_cp, wt_cp, 4096, 1024);
    // 2. LN1
    ln1_kernel<<<M, 256, 0, stream>>>(x, g1, b1, xn);
    // 3. GEMM1 + time-mix (256^2 8-phase; 768 blocks)
    gemm1_kernel<<<768, 512, 0, stream>>>(xn, wt_tm, x, tmk, tmv, tmr, kvbuf, rbuf);
    // 4. WKV chunked parallel scan (x2 -> d_out body, state -> d_out tail)
    {
        const u32* kvp = (const u32*)kvbuf;
        wkv_k1 <<<WKV_THREADS/256, 256, 0, stream>>>(kvp, time_decay, bc);
        wkv_p1 <<<(Bb*C)/256, 256, 0, stream>>>(bc, time_decay, bbin);
        wkv_k2a<<<WKV_THREADS/256, 256, 0, stream>>>(kvp, time_decay, bbin, logS, Rch);
        wkv_p2 <<<(Bb*C)/256, 256, 0, stream>>>(logS, Rch, aain);
        wkv_k2c<<<WKV_THREADS/256, 256, 0, stream>>>(kvp, rbuf, x, time_decay, time_first,
                                                     bbin, aain, x2, out + (size_t)M * C);
    }
    // 5. LN2 + rr + xp snapshot
    ln2_kernel<<<M, 256, 0, stream>>>(x2, g2, b2, cmr, xn, rbuf, xps);
    // 6+7. channel-mix GEMMs in two hidden-halves (h_half overlays dead kv)
    for (int half = 0; half < 2; ++half) {
        const int nbase = half * 2048;
        gemm2_kernel<<<512, 512, 0, stream>>>(
            xn, wt_cm + (size_t)nbase * C, xps, cmk, hbuf, nbase);
        gemm3_kernel<<<256, 512, 0, stream>>>(
            hbuf, wt_cp + nbase, rbuf, out);
    }
}